// Round 5
// baseline (254.646 us; speedup 1.0000x reference)
//
#include <hip/hip_runtime.h>

// Problem dims (fixed by setup_inputs)
#define BB 16
#define CR 1024
#define HWD 784     // 28*28
#define HW2 392     // HWD/2 (float2 units)
#define HW4 196     // HWD/4 (float4 units)
#define CS 256
#define SSZ 25
#define SP 28       // padded row length for kk/M/v (112B = 7 x float4)
#define CI 512
#define CSPLIT 8    // c-chunks in energy (each 128)
#define CCHUNK 128
#define RSPLIT 32   // r-chunks in out (each 32)
#define RCHUNK 32
#define KC 4        // K-split for M partials (128 i each)

// Workspace layout (floats). Total = 3,842,704 floats ~= 15.4 MB.
// Ep region is time-shared: [kk (229376) | P (1835008)] live before k_energy;
// both dead by the time k_energy writes Ep (stream ordering).
#define OFF_POOLED 0          // [B][CS][S]        = 102400
#define OFF_VP     102400     // [B][CR][SP]       = 458752
#define OFF_MP     561152     // [B][CR][SP]       = 458752
#define OFF_E0     1019904    // [B][S]            = 400
#define OFF_ATT    1020304    // [B][S][HW]        = 313600
#define OFF_EP     1333904    // [CSPLIT][B][S][HW]= 2508800
#define OFF_KK     1333904    // alias: [B][CI][SP] = 229376
#define OFF_P      1563280    // alias: [KC][B][4sh][256t][28] = 1835008

// ---------------- K1: pooled = mean over width (rows of 25 floats) ----------------
__global__ __launch_bounds__(256) void k_pool(const float* __restrict__ xs,
                                              float* __restrict__ pooled) {
    __shared__ float buf[4][400];
    int wave = threadIdx.x >> 6, lane = threadIdx.x & 63;
    int r0 = blockIdx.x * 64 + wave * 16;          // 16 rows per wave
    const float4* src = (const float4*)(xs + (size_t)r0 * SSZ);   // 100 float4
    float4* b4 = (float4*)buf[wave];
    b4[lane] = src[lane];
    if (lane < 36) b4[64 + lane] = src[64 + lane];
    __syncthreads();
    if (lane < 16) {
        const float* row = buf[wave] + lane * SSZ;
        float s = 0.f;
#pragma unroll
        for (int w = 0; w < SSZ; ++w) s += row[w];
        pooled[r0 + lane] = s * (1.0f / SSZ);
    }
}

// ---------------- K2: kk = Wk*pooled + bk ; v = Wv*pooled + bv (K=256) ----------------
// LDS-broadcast GEMM: pooled s-slice staged transposed [s][c] (4 KB);
// 3 output rows/thread; 7 s-shards of 4 (shard 6 -> s=24 + zero pads).
// Per c4-iter: 3 coalesced float4 weight loads + 4 broadcast ds_read_b128 + 48 FMA.
__global__ __launch_bounds__(256) void k_kkv(const float* __restrict__ Wk,
                                             const float* __restrict__ Wv,
                                             const float* __restrict__ bk,
                                             const float* __restrict__ bv,
                                             const float* __restrict__ pooled,
                                             float* __restrict__ kk,
                                             float* __restrict__ vp) {
    __shared__ __align__(16) float ldsP[4 * 256];  // [s(4)][c(256)]
    int t = threadIdx.x;
    int rb = blockIdx.x / 7, sh = blockIdx.x % 7;  // rb 0..1, sh 0..6
    int b = blockIdx.y;
    int s0 = sh * 4;
    // stage pooled[b][c][s0..s0+3] -> ldsP[s][c]  (clamp s>24; garbage unused)
    const float* pb = pooled + (size_t)b * CS * SSZ + t * SSZ;
#pragma unroll
    for (int q = 0; q < 4; ++q) {
        int s = s0 + q;
        ldsP[q * 256 + t] = pb[s > 24 ? 24 : s];
    }
    __syncthreads();

    int base = rb * 768;
    int g0 = base + t, g1 = base + 256 + t, g2 = base + 512 + t;
    const float4* w0 = (const float4*)(g0 < 512 ? Wk + (size_t)g0 * CS
                                                : Wv + (size_t)(g0 - 512) * CS);
    const float4* w1 = (const float4*)(g1 < 512 ? Wk + (size_t)g1 * CS
                                                : Wv + (size_t)(g1 - 512) * CS);
    const float4* w2 = (const float4*)(g2 < 512 ? Wk + (size_t)g2 * CS
                                                : Wv + (size_t)(g2 - 512) * CS);
    float acc0[4], acc1[4], acc2[4];
#pragma unroll
    for (int i = 0; i < 4; ++i) { acc0[i] = 0.f; acc1[i] = 0.f; acc2[i] = 0.f; }

#pragma unroll 2
    for (int c4 = 0; c4 < CS / 4; ++c4) {
        float4 a = w0[c4], bw = w1[c4], cw = w2[c4];
#pragma unroll
        for (int s = 0; s < 4; ++s) {
            float4 p = *(const float4*)&ldsP[s * 256 + 4 * c4];   // broadcast
            acc0[s] = fmaf(a.x,  p.x, fmaf(a.y,  p.y, fmaf(a.z,  p.z, fmaf(a.w,  p.w, acc0[s]))));
            acc1[s] = fmaf(bw.x, p.x, fmaf(bw.y, p.y, fmaf(bw.z, p.z, fmaf(bw.w, p.w, acc1[s]))));
            acc2[s] = fmaf(cw.x, p.x, fmaf(cw.y, p.y, fmaf(cw.z, p.z, fmaf(cw.w, p.w, acc2[s]))));
        }
    }

    float bias0 = g0 < 512 ? bk[g0] : bv[g0 - 512];
    float bias1 = g1 < 512 ? bk[g1] : bv[g1 - 512];
    float bias2 = g2 < 512 ? bk[g2] : bv[g2 - 512];
    float* d0 = g0 < 512 ? kk + ((size_t)b * CI + g0) * SP : vp + ((size_t)b * CR + g0 - 512) * SP;
    float* d1 = g1 < 512 ? kk + ((size_t)b * CI + g1) * SP : vp + ((size_t)b * CR + g1 - 512) * SP;
    float* d2 = g2 < 512 ? kk + ((size_t)b * CI + g2) * SP : vp + ((size_t)b * CR + g2 - 512) * SP;
    if (sh < 6) {
#pragma unroll
        for (int i = 0; i < 4; ++i) {
            d0[s0 + i] = acc0[i] + bias0;
            d1[s0 + i] = acc1[i] + bias1;
            d2[s0 + i] = acc2[i] + bias2;
        }
    } else {
        d0[24] = acc0[0] + bias0; d0[25] = 0.f; d0[26] = 0.f; d0[27] = 0.f;
        d1[24] = acc1[0] + bias1; d1[25] = 0.f; d1[26] = 0.f; d1[27] = 0.f;
        d2[24] = acc2[0] + bias2; d2[25] = 0.f; d2[26] = 0.f; d2[27] = 0.f;
    }
}

// ---------------- K3a: M partials via LDS-broadcast GEMM ----------------
__global__ __launch_bounds__(256) void k_Mpart(const float* __restrict__ Wq,
                                               const float* __restrict__ kk,
                                               float* __restrict__ P) {
    __shared__ __align__(16) float lds[128 * 8];   // kk[i-chunk][s-slice(7)+1]
    int sh = blockIdx.x, kc = blockIdx.y, b = blockIdx.z;
    int t = threadIdx.x;
    int s0 = sh * 7;
    int i0 = kc * 128;
    const float* kkb = kk + (size_t)b * CI * SP;
#pragma unroll
    for (int q = 0; q < 4; ++q) {
        int d = t + 256 * q;                       // row=d>>3, col=d&7 (col7 slack)
        lds[d] = kkb[(size_t)(i0 + (d >> 3)) * SP + s0 + (d & 7)];
    }
    __syncthreads();

    float acc[28];
#pragma unroll
    for (int e = 0; e < 28; ++e) acc[e] = 0.f;
    const float4* lds4 = (const float4*)lds;
#pragma unroll 4
    for (int i = 0; i < 128; ++i) {
        float4 w = *(const float4*)(Wq + (size_t)(i0 + i) * CR + 4 * t);  // coalesced
        float4 k0 = lds4[i * 2];
        float4 k1 = lds4[i * 2 + 1];
#pragma unroll
        for (int j = 0; j < 4; ++j) {
            float wj = j == 0 ? w.x : j == 1 ? w.y : j == 2 ? w.z : w.w;
            acc[j * 7 + 0] = fmaf(wj, k0.x, acc[j * 7 + 0]);
            acc[j * 7 + 1] = fmaf(wj, k0.y, acc[j * 7 + 1]);
            acc[j * 7 + 2] = fmaf(wj, k0.z, acc[j * 7 + 2]);
            acc[j * 7 + 3] = fmaf(wj, k0.w, acc[j * 7 + 3]);
            acc[j * 7 + 4] = fmaf(wj, k1.x, acc[j * 7 + 4]);
            acc[j * 7 + 5] = fmaf(wj, k1.y, acc[j * 7 + 5]);
            acc[j * 7 + 6] = fmaf(wj, k1.z, acc[j * 7 + 6]);
        }
    }
    float* dst = P + ((((size_t)kc * BB + b) * 4 + sh) * 256 + t) * 28;
#pragma unroll
    for (int m = 0; m < 7; ++m) {
        float4 o;
        o.x = acc[4 * m + 0]; o.y = acc[4 * m + 1];
        o.z = acc[4 * m + 2]; o.w = acc[4 * m + 3];
        *(float4*)(dst + 4 * m) = o;
    }
}

// ---------------- K3b: Mp[b][c][s] = sum_kc P ----------------
__global__ __launch_bounds__(256) void k_Mred(const float* __restrict__ P,
                                              float* __restrict__ Mp) {
    int id = blockIdx.x * 256 + threadIdx.x;       // 16384 = b*4sh*256t
    int t = id & 255, sh = (id >> 8) & 3, b = id >> 10;
    const float* p0 = P + ((((size_t)b) * 4 + sh) * 256 + t) * 28;
    const size_t PL = (size_t)BB * 4 * 256 * 28;   // 458752 per kc-plane
    float v[28];
#pragma unroll
    for (int m = 0; m < 7; ++m) {
        float4 a = *(const float4*)(p0 + 4 * m);
        float4 b1 = *(const float4*)(p0 + PL + 4 * m);
        float4 c = *(const float4*)(p0 + 2 * PL + 4 * m);
        float4 d = *(const float4*)(p0 + 3 * PL + 4 * m);
        v[4 * m + 0] = a.x + b1.x + c.x + d.x;
        v[4 * m + 1] = a.y + b1.y + c.y + d.y;
        v[4 * m + 2] = a.z + b1.z + c.z + d.z;
        v[4 * m + 3] = a.w + b1.w + c.w + d.w;
    }
    int s0 = sh * 7;
    float* mb = Mp + ((size_t)b * CR + 4 * t) * SP + s0;
#pragma unroll
    for (int j = 0; j < 4; ++j)
#pragma unroll
        for (int u = 0; u < 7; ++u)
            mb[j * SP + u] = v[j * 7 + u];
}

// ---------------- K3c: e0[b][s] = sum_i bq[i]*kk[b][i][s] (wave reduction) ----------------
__global__ __launch_bounds__(64) void k_e0(const float* __restrict__ bq,
                                           const float* __restrict__ kk,
                                           float* __restrict__ e0) {
    int s = blockIdx.x, b = blockIdx.y;
    int l = threadIdx.x;
    const float* kb = kk + (size_t)b * CI * SP;
    float a = 0.f;
#pragma unroll
    for (int k = 0; k < CI / 64; ++k) {
        int i = l + 64 * k;
        a = fmaf(bq[i], kb[(size_t)i * SP + s], a);
    }
#pragma unroll
    for (int off = 32; off > 0; off >>= 1) a += __shfl_down(a, off);
    if (l == 0) e0[b * SSZ + s] = a;
}

// ---------------- K4: partial energies Ep[ch][b][s][n], float4 lanes ----------------
__global__ __launch_bounds__(64) void k_energy(const float* __restrict__ xr,
                                               const float* __restrict__ Mp,
                                               float* __restrict__ Ep) {
    __shared__ float ldsM[CCHUNK * SP];            // 14336 B
    int lane = threadIdx.x;
    int b = blockIdx.y, ch = blockIdx.z;
    int cbeg = ch * CCHUNK;
    {
        const float4* src = (const float4*)(Mp + ((size_t)b * CR + cbeg) * SP);
        float4* dst = (float4*)ldsM;
#pragma unroll
        for (int j = 0; j < 14; ++j) dst[lane + 64 * j] = src[lane + 64 * j];
    }
    __syncthreads();

    int n4 = blockIdx.x * 64 + lane;               // float4 col index
    bool valid = n4 < HW4;
    int n4c = valid ? n4 : 0;
    const float4* x4 = (const float4*)xr + (size_t)b * CR * HW4;

    float4 acc[SSZ];
#pragma unroll
    for (int s = 0; s < SSZ; ++s) acc[s] = make_float4(0.f, 0.f, 0.f, 0.f);

    for (int c = 0; c < CCHUNK; c += 2) {
        float4 xv0 = x4[(size_t)(cbeg + c) * HW4 + n4c];
        float4 xv1 = x4[(size_t)(cbeg + c + 1) * HW4 + n4c];
#pragma unroll
        for (int u = 0; u < 2; ++u) {
            float4 xv = u == 0 ? xv0 : xv1;
            const float4* mr = (const float4*)&ldsM[(c + u) * SP];
#pragma unroll
            for (int j = 0; j < 7; ++j) {
                float4 m = mr[j];
#pragma unroll
                for (int k = 0; k < 4; ++k) {
                    int s = 4 * j + k;
                    if (s < SSZ) {
                        float mv = k == 0 ? m.x : k == 1 ? m.y : k == 2 ? m.z : m.w;
                        acc[s].x = fmaf(xv.x, mv, acc[s].x);
                        acc[s].y = fmaf(xv.y, mv, acc[s].y);
                        acc[s].z = fmaf(xv.z, mv, acc[s].z);
                        acc[s].w = fmaf(xv.w, mv, acc[s].w);
                    }
                }
            }
        }
    }
    if (valid) {
        float4* ep = (float4*)Ep + ((size_t)(ch * BB + b) * SSZ) * HW4 + n4;
#pragma unroll
        for (int s = 0; s < SSZ; ++s) ep[(size_t)s * HW4] = acc[s];
    }
}

// ---------------- K4b: att = softmax_s(sum_ch Ep + e0), float2 lanes ----------------
__global__ __launch_bounds__(64) void k_softmax(const float* __restrict__ Ep,
                                                const float* __restrict__ e0,
                                                float* __restrict__ att) {
    int lane = threadIdx.x;
    int n2 = blockIdx.x * 64 + lane;
    int b = blockIdx.y;
    if (n2 >= HW2) return;
    float ex[SSZ], ey[SSZ];
#pragma unroll
    for (int s = 0; s < SSZ; ++s) { float v = e0[b * SSZ + s]; ex[s] = v; ey[s] = v; }
    const float2* ep2 = (const float2*)Ep;
    for (int ch = 0; ch < CSPLIT; ++ch) {
        const float2* ep = ep2 + ((size_t)(ch * BB + b) * SSZ) * HW2 + n2;
#pragma unroll
        for (int s = 0; s < SSZ; ++s) {
            float2 v = ep[(size_t)s * HW2];
            ex[s] += v.x; ey[s] += v.y;
        }
    }
    float mx = ex[0], my = ey[0];
#pragma unroll
    for (int s = 1; s < SSZ; ++s) { mx = fmaxf(mx, ex[s]); my = fmaxf(my, ey[s]); }
    float sx = 0.f, sy = 0.f;
#pragma unroll
    for (int s = 0; s < SSZ; ++s) {
        ex[s] = __expf(ex[s] - mx); sx += ex[s];
        ey[s] = __expf(ey[s] - my); sy += ey[s];
    }
    float ix = 1.0f / sx, iy = 1.0f / sy;
    float2* ao = (float2*)att + ((size_t)b * SSZ) * HW2 + n2;
#pragma unroll
    for (int s = 0; s < SSZ; ++s) ao[(size_t)s * HW2] = make_float2(ex[s] * ix, ey[s] * iy);
}

// ---------------- K5: out = gamma * (v·att) + x_rgb, float4 lanes ----------------
__global__ __launch_bounds__(64) void k_out(const float* __restrict__ xr,
                                            const float* __restrict__ vp,
                                            const float* __restrict__ att,
                                            const float* __restrict__ gamma,
                                            float* __restrict__ out) {
    __shared__ float ldsv[RCHUNK * SP];            // 3584 B
    int lane = threadIdx.x;
    int b = blockIdx.y, rz = blockIdx.z;
    int r0 = rz * RCHUNK;
    {
        const float4* src = (const float4*)(vp + ((size_t)b * CR + r0) * SP);
        float4* dst = (float4*)ldsv;
#pragma unroll
        for (int j = 0; j < 4; ++j) {
            int idx = lane + 64 * j;
            if (idx < RCHUNK * SP / 4) dst[idx] = src[idx];
        }
    }
    __syncthreads();

    int n4 = blockIdx.x * 64 + lane;
    bool valid = n4 < HW4;
    int n4c = valid ? n4 : 0;

    float4 a[SSZ];
    const float4* at4 = (const float4*)att + ((size_t)b * SSZ) * HW4 + n4c;
#pragma unroll
    for (int s = 0; s < SSZ; ++s) a[s] = at4[(size_t)s * HW4];

    float g = gamma[0];
    const float4* x4 = (const float4*)xr + (size_t)b * CR * HW4;
    float4* o4 = (float4*)out + (size_t)b * CR * HW4;

#pragma unroll 2
    for (int r = 0; r < RCHUNK; ++r) {
        float4 xv = x4[(size_t)(r0 + r) * HW4 + n4c];
        float4 d = make_float4(0.f, 0.f, 0.f, 0.f);
        const float4* vr = (const float4*)&ldsv[r * SP];
#pragma unroll
        for (int j = 0; j < 7; ++j) {
            float4 v = vr[j];
#pragma unroll
            for (int k = 0; k < 4; ++k) {
                int s = 4 * j + k;
                if (s < SSZ) {
                    float vv = k == 0 ? v.x : k == 1 ? v.y : k == 2 ? v.z : v.w;
                    d.x = fmaf(vv, a[s].x, d.x);
                    d.y = fmaf(vv, a[s].y, d.y);
                    d.z = fmaf(vv, a[s].z, d.z);
                    d.w = fmaf(vv, a[s].w, d.w);
                }
            }
        }
        if (valid)
            o4[(size_t)(r0 + r) * HW4 + n4] =
                make_float4(fmaf(g, d.x, xv.x), fmaf(g, d.y, xv.y),
                            fmaf(g, d.z, xv.z), fmaf(g, d.w, xv.w));
    }
}

extern "C" void kernel_launch(void* const* d_in, const int* in_sizes, int n_in,
                              void* d_out, int out_size, void* d_ws, size_t ws_size,
                              hipStream_t stream) {
    const float* x_rgb  = (const float*)d_in[0];
    const float* x_skel = (const float*)d_in[1];
    const float* Wq     = (const float*)d_in[2];
    const float* bq     = (const float*)d_in[3];
    const float* Wk     = (const float*)d_in[4];
    const float* bk     = (const float*)d_in[5];
    const float* Wv     = (const float*)d_in[6];
    const float* bv     = (const float*)d_in[7];
    const float* gamma  = (const float*)d_in[8];
    float* out = (float*)d_out;

    float* ws     = (float*)d_ws;
    float* pooled = ws + OFF_POOLED;
    float* vp     = ws + OFF_VP;
    float* Mp     = ws + OFF_MP;
    float* e0     = ws + OFF_E0;
    float* att    = ws + OFF_ATT;
    float* Ep     = ws + OFF_EP;
    float* kk     = ws + OFF_KK;   // alias into Ep region
    float* P      = ws + OFF_P;    // alias into Ep region

    k_pool   <<<dim3(1600),           256, 0, stream>>>(x_skel, pooled);
    k_kkv    <<<dim3(14, 16),         256, 0, stream>>>(Wk, Wv, bk, bv, pooled, kk, vp);
    k_Mpart  <<<dim3(4, KC, 16),      256, 0, stream>>>(Wq, kk, P);
    k_Mred   <<<dim3(64),             256, 0, stream>>>(P, Mp);
    k_e0     <<<dim3(25, 16),          64, 0, stream>>>(bq, kk, e0);
    k_energy <<<dim3(4, 16, CSPLIT),   64, 0, stream>>>(x_rgb, Mp, Ep);
    k_softmax<<<dim3(7, 16),           64, 0, stream>>>(Ep, e0, att);
    k_out    <<<dim3(4, 16, RSPLIT),   64, 0, stream>>>(x_rgb, vp, att, gamma, out);
}

// Round 6
// 234.390 us; speedup vs baseline: 1.0864x; 1.0864x over previous
//
#include <hip/hip_runtime.h>

// Problem dims (fixed by setup_inputs)
#define BB 16
#define CR 1024
#define HWD 784     // 28*28
#define HW2 392     // HWD/2 (float2 units)
#define CS 256
#define SSZ 25
#define SP 28       // padded row length for kk/M/v (112B = 7 x float4)
#define CI 512
#define CSPLIT 8    // c-chunks in energy (each 128)
#define CCHUNK 128
#define RSPLIT 32   // r-chunks in out (each 32)
#define RCHUNK 32
#define KC 4        // K-split for M partials (128 i each)

// Workspace layout (floats). Total = 3,842,704 floats ~= 15.4 MB.
// Ep region is time-shared: [kk (229376) | P (1835008)] live before k_energy;
// both dead by the time k_energy writes Ep (stream ordering).
#define OFF_POOLED 0          // [B][CS][S]        = 102400
#define OFF_VP     102400     // [B][CR][SP]       = 458752
#define OFF_MP     561152     // [B][CR][SP]       = 458752
#define OFF_E0     1019904    // [B][S]            = 400
#define OFF_ATT    1020304    // [B][S][HW]        = 313600
#define OFF_EP     1333904    // [CSPLIT][B][S][HW]= 2508800
#define OFF_KK     1333904    // alias: [B][CI][SP] = 229376
#define OFF_P      1563280    // alias: [KC][B][4sh][256t][28] = 1835008

// ---------------- K1: pooled = mean over width (rows of 25 floats) ----------------
__global__ __launch_bounds__(256) void k_pool(const float* __restrict__ xs,
                                              float* __restrict__ pooled) {
    __shared__ float buf[4][400];
    int wave = threadIdx.x >> 6, lane = threadIdx.x & 63;
    int r0 = blockIdx.x * 64 + wave * 16;          // 16 rows per wave
    const float4* src = (const float4*)(xs + (size_t)r0 * SSZ);   // 100 float4
    float4* b4 = (float4*)buf[wave];
    b4[lane] = src[lane];
    if (lane < 36) b4[64 + lane] = src[64 + lane];
    __syncthreads();
    if (lane < 16) {
        const float* row = buf[wave] + lane * SSZ;
        float s = 0.f;
#pragma unroll
        for (int w = 0; w < SSZ; ++w) s += row[w];
        pooled[r0 + lane] = s * (1.0f / SSZ);
    }
}

// ---------------- K2: kk = Wk*pooled + bk ; v = Wv*pooled + bv (K=256) ----------------
// LDS-broadcast GEMM: pooled s-slice staged transposed [s][c] (4 KB);
// 3 output rows/thread; 7 s-shards of 4 (shard 6 -> s=24 + zero pads).
__global__ __launch_bounds__(256) void k_kkv(const float* __restrict__ Wk,
                                             const float* __restrict__ Wv,
                                             const float* __restrict__ bk,
                                             const float* __restrict__ bv,
                                             const float* __restrict__ pooled,
                                             float* __restrict__ kk,
                                             float* __restrict__ vp) {
    __shared__ __align__(16) float ldsP[4 * 256];  // [s(4)][c(256)]
    int t = threadIdx.x;
    int rb = blockIdx.x / 7, sh = blockIdx.x % 7;  // rb 0..1, sh 0..6
    int b = blockIdx.y;
    int s0 = sh * 4;
    const float* pb = pooled + (size_t)b * CS * SSZ + t * SSZ;
#pragma unroll
    for (int q = 0; q < 4; ++q) {
        int s = s0 + q;
        ldsP[q * 256 + t] = pb[s > 24 ? 24 : s];
    }
    __syncthreads();

    int base = rb * 768;
    int g0 = base + t, g1 = base + 256 + t, g2 = base + 512 + t;
    const float4* w0 = (const float4*)(g0 < 512 ? Wk + (size_t)g0 * CS
                                                : Wv + (size_t)(g0 - 512) * CS);
    const float4* w1 = (const float4*)(g1 < 512 ? Wk + (size_t)g1 * CS
                                                : Wv + (size_t)(g1 - 512) * CS);
    const float4* w2 = (const float4*)(g2 < 512 ? Wk + (size_t)g2 * CS
                                                : Wv + (size_t)(g2 - 512) * CS);
    float acc0[4], acc1[4], acc2[4];
#pragma unroll
    for (int i = 0; i < 4; ++i) { acc0[i] = 0.f; acc1[i] = 0.f; acc2[i] = 0.f; }

#pragma unroll 2
    for (int c4 = 0; c4 < CS / 4; ++c4) {
        float4 a = w0[c4], bw = w1[c4], cw = w2[c4];
#pragma unroll
        for (int s = 0; s < 4; ++s) {
            float4 p = *(const float4*)&ldsP[s * 256 + 4 * c4];   // broadcast
            acc0[s] = fmaf(a.x,  p.x, fmaf(a.y,  p.y, fmaf(a.z,  p.z, fmaf(a.w,  p.w, acc0[s]))));
            acc1[s] = fmaf(bw.x, p.x, fmaf(bw.y, p.y, fmaf(bw.z, p.z, fmaf(bw.w, p.w, acc1[s]))));
            acc2[s] = fmaf(cw.x, p.x, fmaf(cw.y, p.y, fmaf(cw.z, p.z, fmaf(cw.w, p.w, acc2[s]))));
        }
    }

    float bias0 = g0 < 512 ? bk[g0] : bv[g0 - 512];
    float bias1 = g1 < 512 ? bk[g1] : bv[g1 - 512];
    float bias2 = g2 < 512 ? bk[g2] : bv[g2 - 512];
    float* d0 = g0 < 512 ? kk + ((size_t)b * CI + g0) * SP : vp + ((size_t)b * CR + g0 - 512) * SP;
    float* d1 = g1 < 512 ? kk + ((size_t)b * CI + g1) * SP : vp + ((size_t)b * CR + g1 - 512) * SP;
    float* d2 = g2 < 512 ? kk + ((size_t)b * CI + g2) * SP : vp + ((size_t)b * CR + g2 - 512) * SP;
    if (sh < 6) {
#pragma unroll
        for (int i = 0; i < 4; ++i) {
            d0[s0 + i] = acc0[i] + bias0;
            d1[s0 + i] = acc1[i] + bias1;
            d2[s0 + i] = acc2[i] + bias2;
        }
    } else {
        d0[24] = acc0[0] + bias0; d0[25] = 0.f; d0[26] = 0.f; d0[27] = 0.f;
        d1[24] = acc1[0] + bias1; d1[25] = 0.f; d1[26] = 0.f; d1[27] = 0.f;
        d2[24] = acc2[0] + bias2; d2[25] = 0.f; d2[26] = 0.f; d2[27] = 0.f;
    }
}

// ---------------- K3a: M partials via LDS-broadcast GEMM ----------------
__global__ __launch_bounds__(256) void k_Mpart(const float* __restrict__ Wq,
                                               const float* __restrict__ kk,
                                               float* __restrict__ P) {
    __shared__ __align__(16) float lds[128 * 8];   // kk[i-chunk][s-slice(7)+1]
    int sh = blockIdx.x, kc = blockIdx.y, b = blockIdx.z;
    int t = threadIdx.x;
    int s0 = sh * 7;
    int i0 = kc * 128;
    const float* kkb = kk + (size_t)b * CI * SP;
#pragma unroll
    for (int q = 0; q < 4; ++q) {
        int d = t + 256 * q;                       // row=d>>3, col=d&7 (col7 slack)
        lds[d] = kkb[(size_t)(i0 + (d >> 3)) * SP + s0 + (d & 7)];
    }
    __syncthreads();

    float acc[28];
#pragma unroll
    for (int e = 0; e < 28; ++e) acc[e] = 0.f;
    const float4* lds4 = (const float4*)lds;
#pragma unroll 4
    for (int i = 0; i < 128; ++i) {
        float4 w = *(const float4*)(Wq + (size_t)(i0 + i) * CR + 4 * t);  // coalesced
        float4 k0 = lds4[i * 2];
        float4 k1 = lds4[i * 2 + 1];
#pragma unroll
        for (int j = 0; j < 4; ++j) {
            float wj = j == 0 ? w.x : j == 1 ? w.y : j == 2 ? w.z : w.w;
            acc[j * 7 + 0] = fmaf(wj, k0.x, acc[j * 7 + 0]);
            acc[j * 7 + 1] = fmaf(wj, k0.y, acc[j * 7 + 1]);
            acc[j * 7 + 2] = fmaf(wj, k0.z, acc[j * 7 + 2]);
            acc[j * 7 + 3] = fmaf(wj, k0.w, acc[j * 7 + 3]);
            acc[j * 7 + 4] = fmaf(wj, k1.x, acc[j * 7 + 4]);
            acc[j * 7 + 5] = fmaf(wj, k1.y, acc[j * 7 + 5]);
            acc[j * 7 + 6] = fmaf(wj, k1.z, acc[j * 7 + 6]);
        }
    }
    float* dst = P + ((((size_t)kc * BB + b) * 4 + sh) * 256 + t) * 28;
#pragma unroll
    for (int m = 0; m < 7; ++m) {
        float4 o;
        o.x = acc[4 * m + 0]; o.y = acc[4 * m + 1];
        o.z = acc[4 * m + 2]; o.w = acc[4 * m + 3];
        *(float4*)(dst + 4 * m) = o;
    }
}

// ---------------- K3b: Mp[b][c][s] = sum_kc P  (256 blocks x 64 thr) ----------------
__global__ __launch_bounds__(64) void k_Mred(const float* __restrict__ P,
                                             float* __restrict__ Mp) {
    int id = blockIdx.x * 64 + threadIdx.x;        // 16384 = b*4sh*256t
    int t = id & 255, sh = (id >> 8) & 3, b = id >> 10;
    const float* p0 = P + ((((size_t)b) * 4 + sh) * 256 + t) * 28;
    const size_t PL = (size_t)BB * 4 * 256 * 28;   // 458752 per kc-plane
    float v[28];
#pragma unroll
    for (int m = 0; m < 7; ++m) {
        float4 a = *(const float4*)(p0 + 4 * m);
        float4 b1 = *(const float4*)(p0 + PL + 4 * m);
        float4 c = *(const float4*)(p0 + 2 * PL + 4 * m);
        float4 d = *(const float4*)(p0 + 3 * PL + 4 * m);
        v[4 * m + 0] = a.x + b1.x + c.x + d.x;
        v[4 * m + 1] = a.y + b1.y + c.y + d.y;
        v[4 * m + 2] = a.z + b1.z + c.z + d.z;
        v[4 * m + 3] = a.w + b1.w + c.w + d.w;
    }
    int s0 = sh * 7;
    float* mb = Mp + ((size_t)b * CR + 4 * t) * SP + s0;
#pragma unroll
    for (int j = 0; j < 4; ++j)
#pragma unroll
        for (int u = 0; u < 7; ++u)
            mb[j * SP + u] = v[j * 7 + u];
}

// ---------------- K3c: e0[b][s] = sum_i bq[i]*kk[b][i][s] (wave reduction) ----------------
__global__ __launch_bounds__(64) void k_e0(const float* __restrict__ bq,
                                           const float* __restrict__ kk,
                                           float* __restrict__ e0) {
    int s = blockIdx.x, b = blockIdx.y;
    int l = threadIdx.x;
    const float* kb = kk + (size_t)b * CI * SP;
    float a = 0.f;
#pragma unroll
    for (int k = 0; k < CI / 64; ++k) {
        int i = l + 64 * k;
        a = fmaf(bq[i], kb[(size_t)i * SP + s], a);
    }
#pragma unroll
    for (int off = 32; off > 0; off >>= 1) a += __shfl_down(a, off);
    if (l == 0) e0[b * SSZ + s] = a;
}

// ---------------- K4: partial energies Ep[ch][b][s][n], float2 lanes ----------------
// M chunk (128 x 28) staged in LDS; x loads batched 8-deep for latency hiding.
__global__ __launch_bounds__(64) void k_energy(const float* __restrict__ xr,
                                               const float* __restrict__ Mp,
                                               float* __restrict__ Ep) {
    __shared__ float ldsM[CCHUNK * SP];            // 14336 B
    int lane = threadIdx.x;
    int b = blockIdx.y, ch = blockIdx.z;
    int cbeg = ch * CCHUNK;
    {
        const float4* src = (const float4*)(Mp + ((size_t)b * CR + cbeg) * SP);
        float4* dst = (float4*)ldsM;
#pragma unroll
        for (int j = 0; j < 14; ++j) dst[lane + 64 * j] = src[lane + 64 * j];
    }
    __syncthreads();

    int n2 = blockIdx.x * 64 + lane;
    bool valid = n2 < HW2;
    int n2c = valid ? n2 : 0;
    const float2* x2 = (const float2*)(xr + (size_t)b * CR * HWD);

    float acc0[SP], acc1[SP];
#pragma unroll
    for (int s = 0; s < SP; ++s) { acc0[s] = 0.f; acc1[s] = 0.f; }

    for (int c = 0; c < CCHUNK; c += 8) {
        float2 xv[8];
#pragma unroll
        for (int u = 0; u < 8; ++u)
            xv[u] = x2[(size_t)(cbeg + c + u) * HW2 + n2c];   // 8 loads in flight
#pragma unroll
        for (int u = 0; u < 8; ++u) {
            const float4* mr = (const float4*)&ldsM[(c + u) * SP];
#pragma unroll
            for (int j = 0; j < 7; ++j) {
                float4 m = mr[j];
                acc0[4 * j + 0] = fmaf(xv[u].x, m.x, acc0[4 * j + 0]);
                acc0[4 * j + 1] = fmaf(xv[u].x, m.y, acc0[4 * j + 1]);
                acc0[4 * j + 2] = fmaf(xv[u].x, m.z, acc0[4 * j + 2]);
                acc0[4 * j + 3] = fmaf(xv[u].x, m.w, acc0[4 * j + 3]);
                acc1[4 * j + 0] = fmaf(xv[u].y, m.x, acc1[4 * j + 0]);
                acc1[4 * j + 1] = fmaf(xv[u].y, m.y, acc1[4 * j + 1]);
                acc1[4 * j + 2] = fmaf(xv[u].y, m.z, acc1[4 * j + 2]);
                acc1[4 * j + 3] = fmaf(xv[u].y, m.w, acc1[4 * j + 3]);
            }
        }
    }
    if (valid) {
        float2* ep = (float2*)Ep + ((size_t)(ch * BB + b) * SSZ) * HW2 + n2;
#pragma unroll
        for (int s = 0; s < SSZ; ++s) ep[(size_t)s * HW2] = make_float2(acc0[s], acc1[s]);
    }
}

// ---------------- K4b: att = softmax_s(sum_ch Ep + e0), float2 lanes ----------------
__global__ __launch_bounds__(64) void k_softmax(const float* __restrict__ Ep,
                                                const float* __restrict__ e0,
                                                float* __restrict__ att) {
    int lane = threadIdx.x;
    int n2 = blockIdx.x * 64 + lane;
    int b = blockIdx.y;
    if (n2 >= HW2) return;
    float ex[SSZ], ey[SSZ];
#pragma unroll
    for (int s = 0; s < SSZ; ++s) { float v = e0[b * SSZ + s]; ex[s] = v; ey[s] = v; }
    const float2* ep2 = (const float2*)Ep;
    for (int ch = 0; ch < CSPLIT; ++ch) {
        const float2* ep = ep2 + ((size_t)(ch * BB + b) * SSZ) * HW2 + n2;
#pragma unroll
        for (int s = 0; s < SSZ; ++s) {
            float2 v = ep[(size_t)s * HW2];
            ex[s] += v.x; ey[s] += v.y;
        }
    }
    float mx = ex[0], my = ey[0];
#pragma unroll
    for (int s = 1; s < SSZ; ++s) { mx = fmaxf(mx, ex[s]); my = fmaxf(my, ey[s]); }
    float sx = 0.f, sy = 0.f;
#pragma unroll
    for (int s = 0; s < SSZ; ++s) {
        ex[s] = __expf(ex[s] - mx); sx += ex[s];
        ey[s] = __expf(ey[s] - my); sy += ey[s];
    }
    float ix = 1.0f / sx, iy = 1.0f / sy;
    float2* ao = (float2*)att + ((size_t)b * SSZ) * HW2 + n2;
#pragma unroll
    for (int s = 0; s < SSZ; ++s) ao[(size_t)s * HW2] = make_float2(ex[s] * ix, ey[s] * iy);
}

// ---------------- K5: out = gamma * (v·att) + x_rgb, float2 lanes ----------------
__global__ __launch_bounds__(64) void k_out(const float* __restrict__ xr,
                                            const float* __restrict__ vp,
                                            const float* __restrict__ att,
                                            const float* __restrict__ gamma,
                                            float* __restrict__ out) {
    __shared__ float ldsv[RCHUNK * SP];            // 3584 B
    int lane = threadIdx.x;
    int b = blockIdx.y, rz = blockIdx.z;
    int r0 = rz * RCHUNK;
    {
        const float4* src = (const float4*)(vp + ((size_t)b * CR + r0) * SP);
        float4* dst = (float4*)ldsv;
#pragma unroll
        for (int j = 0; j < 4; ++j) {
            int idx = lane + 64 * j;
            if (idx < RCHUNK * SP / 4) dst[idx] = src[idx];
        }
    }
    __syncthreads();

    int n2 = blockIdx.x * 64 + lane;
    bool valid = n2 < HW2;
    int n2c = valid ? n2 : 0;

    float a0[SP], a1[SP];
    const float2* at2 = (const float2*)att + ((size_t)b * SSZ) * HW2 + n2c;
#pragma unroll
    for (int s = 0; s < SSZ; ++s) {
        float2 av = at2[(size_t)s * HW2];
        a0[s] = av.x; a1[s] = av.y;
    }
#pragma unroll
    for (int s = SSZ; s < SP; ++s) { a0[s] = 0.f; a1[s] = 0.f; }

    float g = gamma[0];
    const float2* x2 = (const float2*)(xr + (size_t)b * CR * HWD);
    float2* o2 = (float2*)(out + (size_t)b * CR * HWD);

#pragma unroll 4
    for (int r = 0; r < RCHUNK; ++r) {
        float2 xv = x2[(size_t)(r0 + r) * HW2 + n2c];
        float d0 = 0.f, d1 = 0.f;
        const float4* vr = (const float4*)&ldsv[r * SP];
#pragma unroll
        for (int j = 0; j < 7; ++j) {
            float4 v = vr[j];
            d0 = fmaf(v.x, a0[4 * j + 0], d0);
            d0 = fmaf(v.y, a0[4 * j + 1], d0);
            d0 = fmaf(v.z, a0[4 * j + 2], d0);
            d0 = fmaf(v.w, a0[4 * j + 3], d0);
            d1 = fmaf(v.x, a1[4 * j + 0], d1);
            d1 = fmaf(v.y, a1[4 * j + 1], d1);
            d1 = fmaf(v.z, a1[4 * j + 2], d1);
            d1 = fmaf(v.w, a1[4 * j + 3], d1);
        }
        if (valid)
            o2[(size_t)(r0 + r) * HW2 + n2] = make_float2(fmaf(g, d0, xv.x), fmaf(g, d1, xv.y));
    }
}

extern "C" void kernel_launch(void* const* d_in, const int* in_sizes, int n_in,
                              void* d_out, int out_size, void* d_ws, size_t ws_size,
                              hipStream_t stream) {
    const float* x_rgb  = (const float*)d_in[0];
    const float* x_skel = (const float*)d_in[1];
    const float* Wq     = (const float*)d_in[2];
    const float* bq     = (const float*)d_in[3];
    const float* Wk     = (const float*)d_in[4];
    const float* bk     = (const float*)d_in[5];
    const float* Wv     = (const float*)d_in[6];
    const float* bv     = (const float*)d_in[7];
    const float* gamma  = (const float*)d_in[8];
    float* out = (float*)d_out;

    float* ws     = (float*)d_ws;
    float* pooled = ws + OFF_POOLED;
    float* vp     = ws + OFF_VP;
    float* Mp     = ws + OFF_MP;
    float* e0     = ws + OFF_E0;
    float* att    = ws + OFF_ATT;
    float* Ep     = ws + OFF_EP;
    float* kk     = ws + OFF_KK;   // alias into Ep region
    float* P      = ws + OFF_P;    // alias into Ep region

    k_pool   <<<dim3(1600),           256, 0, stream>>>(x_skel, pooled);
    k_kkv    <<<dim3(14, 16),         256, 0, stream>>>(Wk, Wv, bk, bv, pooled, kk, vp);
    k_Mpart  <<<dim3(4, KC, 16),      256, 0, stream>>>(Wq, kk, P);
    k_Mred   <<<dim3(256),             64, 0, stream>>>(P, Mp);
    k_e0     <<<dim3(25, 16),          64, 0, stream>>>(bq, kk, e0);
    k_energy <<<dim3(7, 16, CSPLIT),   64, 0, stream>>>(x_rgb, Mp, Ep);
    k_softmax<<<dim3(7, 16),           64, 0, stream>>>(Ep, e0, att);
    k_out    <<<dim3(7, 16, RSPLIT),   64, 0, stream>>>(x_rgb, vp, att, gamma, out);
}